// Round 9
// baseline (327.465 us; speedup 1.0000x reference)
//
#include <hip/hip_runtime.h>

#define EMB_N 50
#define KP 64            // bf16 plane row width (k padded 50->64)
#define LQ 32
#define LD 256
#define KN 21
#define BATCH 2048
#define VROWS 64         // vocab rows staged per block in vocab_norm

typedef short v8s __attribute__((ext_vector_type(8)));   // 8 bf16 = one MFMA frag
typedef float v4f __attribute__((ext_vector_type(4)));
typedef float v2f __attribute__((ext_vector_type(2)));

// Guaranteed packed-fp32 ops (VOP3P); tied accumulator avoids extra moves.
#define PK_ACC(d, b)    asm("v_pk_add_f32 %0, %0, %1" : "+v"(d) : "v"(b))
#define PK_MULA(d, b)   asm("v_pk_mul_f32 %0, %0, %1" : "+v"(d) : "v"(b))

__device__ inline short bf16_rne(float f) {      // round-to-nearest-even bf16
  unsigned u = __float_as_uint(f);
  unsigned r = u + 0x7fffu + ((u >> 16) & 1u);
  return (short)(r >> 16);
}
__device__ inline float bf16_tof(short h) {
  return __uint_as_float(((unsigned)(unsigned short)h) << 16);
}

// ---------- Kernel 0: normalize vocab -> bf16 rne plane + residual plane ----------
// v2: block of 512 stages 64 rows (12.8 KB) into LDS with fully-coalesced
// float4 stream loads (the old version's 8-thread/row strided float2 reads hit
// ~25% line utilization), then the identical normalize/convert path runs out
// of LDS. Writes (16B/thread, contiguous across the block) were already ideal.
__global__ __launch_bounds__(512) void vocab_norm_kernel(
    const float* __restrict__ emb, short* __restrict__ vb,
    short* __restrict__ vlo, int vocab)
{
  __shared__ float lds[VROWS * EMB_N];           // 12800 B
  const int tid = threadIdx.x;
  const long long ftotal = (long long)vocab * EMB_N;
  const long long fbase  = (long long)blockIdx.x * (VROWS * EMB_N);

  // ---- stage: 800 float4 per block, coalesced ----
  const float4* e4 = (const float4*)emb;
#pragma unroll
  for (int i = 0; i < 2; i++) {
    int idx = i * 512 + tid;
    if (idx < (VROWS * EMB_N) / 4) {
      long long g4 = fbase / 4 + idx;
      if (g4 * 4 + 3 < ftotal) {
        *(float4*)&lds[idx * 4] = e4[g4];
      } else {                                    // ragged tail (safety)
#pragma unroll
        for (int k = 0; k < 4; k++) {
          long long gf = g4 * 4 + k;
          lds[idx * 4 + k] = (gf < ftotal) ? emb[gf] : 0.f;
        }
      }
    }
  }
  __syncthreads();

  // ---- compute: 8 threads per row, reading LDS ----
  const int r = tid >> 3;                         // row-in-block 0..63
  const int c = tid & 7;                          // 8-elem chunk
  const int row = blockIdx.x * VROWS + r;
  if (row >= vocab) return;

  float v[8];
#pragma unroll
  for (int k = 0; k < 8; k++) v[k] = 0.f;
  float ss = 0.f;
  const int e0 = c * 8;
  const int cnt = (c < 6) ? 8 : (c == 6 ? 2 : 0);
  for (int k = 0; k < cnt; k++) {
    float t = lds[r * EMB_N + e0 + k];
    v[k] = t;
    ss = fmaf(t, t, ss);
  }
  ss += __shfl_xor(ss, 1);
  ss += __shfl_xor(ss, 2);
  ss += __shfl_xor(ss, 4);
  float inv = 1.0f / (sqrtf(ss) + 1e-13f);        // matches ref x/(norm+1e-13)
  short hi[8], lo[8];
#pragma unroll
  for (int k = 0; k < 8; k++) {
    float f = v[k] * inv;
    hi[k] = bf16_rne(f);                          // doc plane: rne (unbiased)
    lo[k] = bf16_rne(f - bf16_tof(hi[k]));        // query residual
  }
  size_t o = (size_t)row * KP + e0;               // 16B aligned
  *(uint4*)(vb + o)  = *(const uint4*)hi;
  *(uint4*)(vlo + o) = *(const uint4*)lo;
}

// Cj = exp(-50*mu_j^2), mu_j = -0.95 + 0.1*j (j=0..19); Cj[20]=1 (exact kernel)
__device__ __constant__ const float CJ[KN] = {
  2.5261639e-20f, 2.0469719e-16f, 6.1019363e-13f, 6.6915861e-10f, 2.6995785e-7f,
  4.0065297e-5f,  2.1874911e-3f,  4.3936937e-2f,  0.32465247f,    0.88249690f,
  0.88249690f,    0.32465247f,    4.3936937e-2f,  2.1874911e-3f,  4.0065297e-5f,
  2.6995785e-7f,  6.6915861e-10f, 6.1019363e-13f, 2.0469719e-16f, 2.5261639e-20f,
  1.0f
};

// ---------- Main kernel: one workgroup per (item, pair), fused MFMA+RBF ----------
// Round-8 proven config (VGPR=32, no spill, 71% occupancy). Combine step is
// fused: the second-finishing block of each item computes sigmoid(lg1-lg2)
// via a per-item flag (release/acquire atomics, device scope).
__global__ __launch_bounds__(256, 6) void knrm_main_kernel(
    const short* __restrict__ vb, const short* __restrict__ vlo,
    const int* __restrict__ q1, const int* __restrict__ d1,
    const int* __restrict__ q2, const int* __restrict__ d2,
    const float* __restrict__ w0, const float* __restrict__ b0,
    const float* __restrict__ w1, const float* __restrict__ b1,
    const float* __restrict__ w2, const float* __restrict__ b2,
    float* __restrict__ lgbuf, int* __restrict__ flags,
    float* __restrict__ out)
{
  __shared__ float part[4][16][KN];  // per-wave partial S[q-in-tile][j]  (5376 B)
  __shared__ float Sqex[LQ];         // exact-match counts per query
  __shared__ float ko[KN];
  __shared__ float h0s[10];
  __shared__ float h1s[5];

  const int pair = blockIdx.x >> 11;         // 0..1
  const int b = blockIdx.x & (BATCH - 1);    // item
  const int tid = threadIdx.x;
  const int wave = tid >> 6;                 // 0..3
  const int lane = tid & 63;
  const int l15 = lane & 15;
  const int quad = lane >> 4;
  const int qtile = wave >> 1;               // waves 0,1 -> queries 0-15; 2,3 -> 16-31
  const int thalf = wave & 1;                // doc-tile half: tiles thalf*8 .. +7

  const int* qp = pair ? q2 : q1;
  const int* dp = pair ? d2 : d1;

  if (tid < LQ) Sqex[tid] = 0.f;

  // ---- query B-frags (hi + lo planes), token = qtile*16 + l15 ----
  int qtok = qp[b * LQ + qtile * 16 + l15];
  const short* qh = vb  + (size_t)qtok * KP + quad * 8;
  const short* ql = vlo + (size_t)qtok * KP + quad * 8;
  v8s Bh0 = *(const v8s*)(qh);
  v8s Bh1 = *(const v8s*)(qh + 32);
  v8s Bl0 = *(const v8s*)(ql);
  v8s Bl1 = *(const v8s*)(ql + 32);

  int mydtok = dp[b * LD + tid];             // for exact-match ballot

  __syncthreads();   // Sqex init visible before atomics

  // ---- exact kernel (sigma=1e-3): integer token match count ----
  // exp(-5e5(mm-1)^2) == 1 iff dtok==qtok!=0 (token-0 row is zero -> mm=0);
  // random cross-token cos>0.9 has probability ~5e-18 -> negligible.
#pragma unroll
  for (int qq = 0; qq < LQ; qq++) {
    int qt = qp[b * LQ + qq];                     // uniform -> s_load
    unsigned long long m = __ballot(mydtok == qt && qt != 0);
    if (lane == 0 && m)
      atomicAdd(&Sqex[qq], (float)__popcll(m));   // fires ~never
  }

  // ---- fused: per 16-doc tile, MFMA then RBF directly on C registers ----
  // C layout: row = quad*4+reg = doc, col = l15 = query -> each lane: 4 docs,
  // one query -> accumulate into its own U2 (20 kernels, packed up/down chains).
  v2f U2[10];                       // .x: j=10+i (up), .y: j=9-i (down)
#pragma unroll
  for (int i = 0; i < 10; i++) U2[i] = (v2f){0.f, 0.f};

#pragma unroll 1
  for (int t = 0; t < 8; t++) {
    int dtok = dp[b * LD + (thalf * 8 + t) * 16 + l15];   // L1-hot re-load
    const short* dptr = vb + (size_t)dtok * KP + quad * 8;
    v8s A0 = *(const v8s*)(dptr);
    v8s A1 = *(const v8s*)(dptr + 32);

    v4f C = {0.f, 0.f, 0.f, 0.f};
    C = __builtin_amdgcn_mfma_f32_16x16x32_bf16(A0, Bh0, C, 0, 0, 0);
    C = __builtin_amdgcn_mfma_f32_16x16x32_bf16(A1, Bh1, C, 0, 0, 0);
    C = __builtin_amdgcn_mfma_f32_16x16x32_bf16(A0, Bl0, C, 0, 0, 0);
    C = __builtin_amdgcn_mfma_f32_16x16x32_bf16(A1, Bl1, C, 0, 0, 0);

    // F_j(x) = gc * rr^(j-10) * Cj, gc = exp(-50x^2+5x), rr = exp(10x).
    // Two 2-row passes: only p0/p1/rr0/rr1 live (8 regs).
#pragma unroll
    for (int rp = 0; rp < 2; rp++) {
      v2f p0, p1, rr0, rr1;
      {
        float x = C[rp * 2];
        float gc = __builtin_amdgcn_exp2f(x * fmaf(-72.1347520f, x, 7.2134752f));
        float ex = 14.4269504f * x;
        float e1 = __builtin_amdgcn_exp2f(ex);
        float ei = __builtin_amdgcn_exp2f(-ex);
        p0 = (v2f){gc, gc * ei};  rr0 = (v2f){e1, ei};
      }
      {
        float x = C[rp * 2 + 1];
        float gc = __builtin_amdgcn_exp2f(x * fmaf(-72.1347520f, x, 7.2134752f));
        float ex = 14.4269504f * x;
        float e1 = __builtin_amdgcn_exp2f(ex);
        float ei = __builtin_amdgcn_exp2f(-ex);
        p1 = (v2f){gc, gc * ei};  rr1 = (v2f){e1, ei};
      }
#pragma unroll
      for (int k2 = 0; k2 < 10; k2++) {
        PK_ACC(U2[k2], p0);
        PK_MULA(p0, rr0);
        PK_ACC(U2[k2], p1);
        PK_MULA(p1, rr1);
      }
    }
  }

  // ---- butterfly over quad bits (docs), park per-wave partials ----
#pragma unroll
  for (int i = 0; i < 10; i++) {
    float ux = U2[i].x, uy = U2[i].y;
    ux += __shfl_xor(ux, 16);  uy += __shfl_xor(uy, 16);
    ux += __shfl_xor(ux, 32);  uy += __shfl_xor(uy, 32);
    if (quad == 0) {
      part[wave][l15][10 + i] = ux;   // up chain  j = 10+i
      part[wave][l15][9 - i]  = uy;   // down chain j = 9-i
    }
  }
  __syncthreads();

  // ---- cooperative log1p + q-reduction into ko[j] (no atomics) ----
  {
    int qq = tid & 31;                 // query
    int qi = qq & 15, qt2 = qq >> 4;
    int jb = tid >> 5;                 // 0..7
#pragma unroll
    for (int k = 0; k < 3; k++) {
      int j = jb + 8 * k;
      float l = 0.f;
      if (j < KN) {
        float s = (j < 20) ? part[qt2 * 2][qi][j] + part[qt2 * 2 + 1][qi][j]
                           : Sqex[qq];
        float y = fmaf(CJ[j], s, 1.0f);                     // y >= 1
        l = 0.69314718f * __builtin_amdgcn_logf(y);         // log1p
      }
      l += __shfl_xor(l, 1);  l += __shfl_xor(l, 2);
      l += __shfl_xor(l, 4);  l += __shfl_xor(l, 8);
      l += __shfl_xor(l, 16);                               // sum over 32 queries
      if (qq == 0 && j < KN) ko[j] = l;
    }
  }
  __syncthreads();

  // ---- tiny MLP: 21 -> 10 -> 5 -> 1 ----
  if (tid < 10) {
    float h = b0[tid];
#pragma unroll
    for (int k = 0; k < KN; k++) h = fmaf(w0[tid * KN + k], ko[k], h);
    h0s[tid] = fmaxf(h, 0.f);
  }
  __syncthreads();
  if (tid < 5) {
    float h = b1[tid];
#pragma unroll
    for (int k = 0; k < 10; k++) h = fmaf(w1[tid * 10 + k], h0s[k], h);
    h1s[tid] = fmaxf(h, 0.f);
  }
  __syncthreads();
  if (tid == 0) {
    float h = b2[0];
#pragma unroll
    for (int k = 0; k < 5; k++) h = fmaf(w2[k], h1s[k], h);
    // fused combine: second finisher for item b computes sigmoid(lg1 - lg2)
    __hip_atomic_store(&lgbuf[pair * BATCH + b], h,
                       __ATOMIC_RELEASE, __HIP_MEMORY_SCOPE_AGENT);
    int old = __hip_atomic_fetch_add(&flags[b], 1,
                                     __ATOMIC_ACQ_REL, __HIP_MEMORY_SCOPE_AGENT);
    if (old == 1) {
      float other = __hip_atomic_load(&lgbuf[(1 - pair) * BATCH + b],
                                      __ATOMIC_ACQUIRE, __HIP_MEMORY_SCOPE_AGENT);
      float z = pair ? (other - h) : (h - other);
      out[b] = 1.0f / (1.0f + __expf(-z));
    }
  }
}

// ---------------- launch ----------------
extern "C" void kernel_launch(void* const* d_in, const int* in_sizes, int n_in,
                              void* d_out, int out_size, void* d_ws, size_t ws_size,
                              hipStream_t stream)
{
  const float* emb = (const float*)d_in[0];
  const float* w0  = (const float*)d_in[1];
  const float* b0  = (const float*)d_in[2];
  const float* w1  = (const float*)d_in[3];
  const float* b1  = (const float*)d_in[4];
  const float* w2  = (const float*)d_in[5];
  const float* b2  = (const float*)d_in[6];
  const int* q1 = (const int*)d_in[7];
  const int* dd1 = (const int*)d_in[8];
  const int* q2 = (const int*)d_in[9];
  const int* dd2 = (const int*)d_in[10];
  float* out = (float*)d_out;

  int vocab = in_sizes[0] / EMB_N;      // 100000
  int B = in_sizes[7] / LQ;             // 2048

  float* lgbuf = (float*)d_ws;                          // 2*B floats = 16 KB
  int*   flags = (int*)(lgbuf + 2 * BATCH);             // B ints = 8 KB
  short* vb  = (short*)(flags + BATCH);                 // 12.8 MB (rne plane)
  short* vlo = vb + (size_t)vocab * KP;                 // 12.8 MB (residual)

  hipMemsetAsync(flags, 0, BATCH * sizeof(int), stream);
  vocab_norm_kernel<<<(vocab + VROWS - 1) / VROWS, 512, 0, stream>>>(emb, vb, vlo, vocab);
  knrm_main_kernel<<<2 * B, 256, 0, stream>>>(vb, vlo, q1, dd1, q2, dd2,
                                              w0, b0, w1, b1, w2, b2,
                                              lgbuf, flags, out);
}

// Round 10
// 141.881 us; speedup vs baseline: 2.3080x; 2.3080x over previous
//
#include <hip/hip_runtime.h>

#define EMB_N 50
#define KP 64            // bf16 plane row width (k padded 50->64)
#define LQ 32
#define LD 256
#define KN 21
#define BATCH 2048
#define VROWS 64         // vocab rows staged per block in vocab_norm

typedef short v8s __attribute__((ext_vector_type(8)));   // 8 bf16 = one MFMA frag
typedef float v4f __attribute__((ext_vector_type(4)));
typedef float v2f __attribute__((ext_vector_type(2)));

// Guaranteed packed-fp32 ops (VOP3P); tied operands avoid extra moves.
#define PK_ACC(d, b)     asm("v_pk_add_f32 %0, %0, %1" : "+v"(d) : "v"(b))
#define PK_MULA(d, b)    asm("v_pk_mul_f32 %0, %0, %1" : "+v"(d) : "v"(b))
#define PK_FMA(d, a, b)  asm("v_pk_fma_f32 %0, %1, %2, %0" : "+v"(d) : "v"(a), "v"(b))

__device__ inline short bf16_rne(float f) {      // round-to-nearest-even bf16
  unsigned u = __float_as_uint(f);
  unsigned r = u + 0x7fffu + ((u >> 16) & 1u);
  return (short)(r >> 16);
}
__device__ inline float bf16_tof(short h) {
  return __uint_as_float(((unsigned)(unsigned short)h) << 16);
}

// ---------- Kernel 0: normalize vocab -> bf16 rne plane + residual plane ----------
// Block of 512 stages 64 rows (12.8 KB) into LDS with coalesced float4 loads,
// then the per-thread normalize/convert path reads LDS. Writes already ideal.
__global__ __launch_bounds__(512) void vocab_norm_kernel(
    const float* __restrict__ emb, short* __restrict__ vb,
    short* __restrict__ vlo, int vocab)
{
  __shared__ float lds[VROWS * EMB_N];           // 12800 B
  const int tid = threadIdx.x;
  const long long ftotal = (long long)vocab * EMB_N;
  const long long fbase  = (long long)blockIdx.x * (VROWS * EMB_N);

  const float4* e4 = (const float4*)emb;
#pragma unroll
  for (int i = 0; i < 2; i++) {
    int idx = i * 512 + tid;
    if (idx < (VROWS * EMB_N) / 4) {
      long long g4 = fbase / 4 + idx;
      if (g4 * 4 + 3 < ftotal) {
        *(float4*)&lds[idx * 4] = e4[g4];
      } else {                                    // ragged tail (safety)
#pragma unroll
        for (int k = 0; k < 4; k++) {
          long long gf = g4 * 4 + k;
          lds[idx * 4 + k] = (gf < ftotal) ? emb[gf] : 0.f;
        }
      }
    }
  }
  __syncthreads();

  const int r = tid >> 3;                         // row-in-block 0..63
  const int c = tid & 7;                          // 8-elem chunk
  const int row = blockIdx.x * VROWS + r;
  if (row >= vocab) return;

  float v[8];
#pragma unroll
  for (int k = 0; k < 8; k++) v[k] = 0.f;
  float ss = 0.f;
  const int e0 = c * 8;
  const int cnt = (c < 6) ? 8 : (c == 6 ? 2 : 0);
  for (int k = 0; k < cnt; k++) {
    float t = lds[r * EMB_N + e0 + k];
    v[k] = t;
    ss = fmaf(t, t, ss);
  }
  ss += __shfl_xor(ss, 1);
  ss += __shfl_xor(ss, 2);
  ss += __shfl_xor(ss, 4);
  float inv = 1.0f / (sqrtf(ss) + 1e-13f);        // matches ref x/(norm+1e-13)
  short hi[8], lo[8];
#pragma unroll
  for (int k = 0; k < 8; k++) {
    float f = v[k] * inv;
    hi[k] = bf16_rne(f);                          // doc plane: rne (unbiased)
    lo[k] = bf16_rne(f - bf16_tof(hi[k]));        // query residual
  }
  size_t o = (size_t)row * KP + e0;               // 16B aligned
  *(uint4*)(vb + o)  = *(const uint4*)hi;
  *(uint4*)(vlo + o) = *(const uint4*)lo;
}

// Cj = exp(-50*mu_j^2), mu_j = -0.95 + 0.1*j (j=0..19); Cj[20]=1 (exact kernel)
__device__ __constant__ const float CJ[KN] = {
  2.5261639e-20f, 2.0469719e-16f, 6.1019363e-13f, 6.6915861e-10f, 2.6995785e-7f,
  4.0065297e-5f,  2.1874911e-3f,  4.3936937e-2f,  0.32465247f,    0.88249690f,
  0.88249690f,    0.32465247f,    4.3936937e-2f,  2.1874911e-3f,  4.0065297e-5f,
  2.6995785e-7f,  6.6915861e-10f, 6.1019363e-13f, 2.0469719e-16f, 2.5261639e-20f,
  1.0f
};

// ---------- Main kernel: one workgroup per (item, pair), fused MFMA+RBF ----------
// Round-8 proven shell (VGPR=32, no spill, ~71% occupancy). Plain global
// stores in the epilogue -- NO agent-scope acquire/release atomics: round 9
// showed they emit per-block L2 writeback/invalidate, killing the embedding
// cache for all resident blocks (58 -> 243 us).
// RBF chain now fma-paired: {U[2m]+=p; U[2m+1]=fma(p,rr,U[2m+1]); p*=rr^2} --
// 3 VOP3P per 2 kernels instead of 4. v_pk_f32 ops cost 4 cy/wave on the
// 32-lane SIMD (2x32 f32 ALUs), so the chain IS the measured VALU-busy floor;
// this cuts it 25%.
__global__ __launch_bounds__(256, 6) void knrm_main_kernel(
    const short* __restrict__ vb, const short* __restrict__ vlo,
    const int* __restrict__ q1, const int* __restrict__ d1,
    const int* __restrict__ q2, const int* __restrict__ d2,
    const float* __restrict__ w0, const float* __restrict__ b0,
    const float* __restrict__ w1, const float* __restrict__ b1,
    const float* __restrict__ w2, const float* __restrict__ b2,
    float* __restrict__ lgbuf)
{
  __shared__ float part[4][16][KN];  // per-wave partial S[q-in-tile][j]  (5376 B)
  __shared__ float Sqex[LQ];         // exact-match counts per query
  __shared__ float ko[KN];
  __shared__ float h0s[10];
  __shared__ float h1s[5];

  const int pair = blockIdx.x >> 11;         // 0..1
  const int b = blockIdx.x & (BATCH - 1);    // item
  const int tid = threadIdx.x;
  const int wave = tid >> 6;                 // 0..3
  const int lane = tid & 63;
  const int l15 = lane & 15;
  const int quad = lane >> 4;
  const int qtile = wave >> 1;               // waves 0,1 -> queries 0-15; 2,3 -> 16-31
  const int thalf = wave & 1;                // doc-tile half: tiles thalf*8 .. +7

  const int* qp = pair ? q2 : q1;
  const int* dp = pair ? d2 : d1;

  if (tid < LQ) Sqex[tid] = 0.f;

  // ---- query B-frags (hi + lo planes), token = qtile*16 + l15 ----
  int qtok = qp[b * LQ + qtile * 16 + l15];
  const short* qh = vb  + (size_t)qtok * KP + quad * 8;
  const short* ql = vlo + (size_t)qtok * KP + quad * 8;
  v8s Bh0 = *(const v8s*)(qh);
  v8s Bh1 = *(const v8s*)(qh + 32);
  v8s Bl0 = *(const v8s*)(ql);
  v8s Bl1 = *(const v8s*)(ql + 32);

  int mydtok = dp[b * LD + tid];             // for exact-match ballot

  __syncthreads();   // Sqex init visible before atomics

  // ---- exact kernel (sigma=1e-3): integer token match count ----
  // exp(-5e5(mm-1)^2) == 1 iff dtok==qtok!=0 (token-0 row is zero -> mm=0);
  // random cross-token cos>0.9 has probability ~5e-18 -> negligible.
#pragma unroll
  for (int qq = 0; qq < LQ; qq++) {
    int qt = qp[b * LQ + qq];                     // uniform -> s_load
    unsigned long long m = __ballot(mydtok == qt && qt != 0);
    if (lane == 0 && m)
      atomicAdd(&Sqex[qq], (float)__popcll(m));   // fires ~never
  }

  // ---- fused: per 16-doc tile, MFMA then RBF directly on C registers ----
  // C layout: row = quad*4+reg = doc, col = l15 = query -> each lane: 4 docs,
  // one query -> accumulate into its own U2 (20 kernels, packed up/down chains).
  v2f U2[10];                       // .x: j=10+i (up), .y: j=9-i (down)
#pragma unroll
  for (int i = 0; i < 10; i++) U2[i] = (v2f){0.f, 0.f};

#pragma unroll 1
  for (int t = 0; t < 8; t++) {
    int dtok = dp[b * LD + (thalf * 8 + t) * 16 + l15];   // L1-hot re-load
    const short* dptr = vb + (size_t)dtok * KP + quad * 8;
    v8s A0 = *(const v8s*)(dptr);
    v8s A1 = *(const v8s*)(dptr + 32);

    v4f C = {0.f, 0.f, 0.f, 0.f};
    C = __builtin_amdgcn_mfma_f32_16x16x32_bf16(A0, Bh0, C, 0, 0, 0);
    C = __builtin_amdgcn_mfma_f32_16x16x32_bf16(A1, Bh1, C, 0, 0, 0);
    C = __builtin_amdgcn_mfma_f32_16x16x32_bf16(A0, Bl0, C, 0, 0, 0);
    C = __builtin_amdgcn_mfma_f32_16x16x32_bf16(A1, Bl1, C, 0, 0, 0);

    // F_j(x) = gc * rr^(j-10) * Cj, gc = exp(-50x^2+5x), rr = exp(10x).
    // Two 2-row passes; per row-stream the fma-paired chain:
    //   p = gc*rr^(2m): U2[2m] += p; U2[2m+1] += p*rr (fma); p *= rr^2.
#pragma unroll
    for (int rp = 0; rp < 2; rp++) {
      v2f p0, p1, rr0, rr1;
      {
        float x = C[rp * 2];
        float gc = __builtin_amdgcn_exp2f(x * fmaf(-72.1347520f, x, 7.2134752f));
        float ex = 14.4269504f * x;
        float e1 = __builtin_amdgcn_exp2f(ex);
        float ei = __builtin_amdgcn_exp2f(-ex);
        p0 = (v2f){gc, gc * ei};  rr0 = (v2f){e1, ei};
      }
      {
        float x = C[rp * 2 + 1];
        float gc = __builtin_amdgcn_exp2f(x * fmaf(-72.1347520f, x, 7.2134752f));
        float ex = 14.4269504f * x;
        float e1 = __builtin_amdgcn_exp2f(ex);
        float ei = __builtin_amdgcn_exp2f(-ex);
        p1 = (v2f){gc, gc * ei};  rr1 = (v2f){e1, ei};
      }
      v2f s0 = rr0, s1 = rr1;
      PK_MULA(s0, rr0);                            // rr^2
      PK_MULA(s1, rr1);
#pragma unroll
      for (int m = 0; m < 5; m++) {
        PK_ACC(U2[2 * m], p0);
        PK_FMA(U2[2 * m + 1], p0, rr0);
        if (m < 4) PK_MULA(p0, s0);
        PK_ACC(U2[2 * m], p1);
        PK_FMA(U2[2 * m + 1], p1, rr1);
        if (m < 4) PK_MULA(p1, s1);
      }
    }
  }

  // ---- butterfly over quad bits (docs), park per-wave partials ----
#pragma unroll
  for (int i = 0; i < 10; i++) {
    float ux = U2[i].x, uy = U2[i].y;
    ux += __shfl_xor(ux, 16);  uy += __shfl_xor(uy, 16);
    ux += __shfl_xor(ux, 32);  uy += __shfl_xor(uy, 32);
    if (quad == 0) {
      part[wave][l15][10 + i] = ux;   // up chain  j = 10+i
      part[wave][l15][9 - i]  = uy;   // down chain j = 9-i
    }
  }
  __syncthreads();

  // ---- cooperative log1p + q-reduction into ko[j] (no atomics) ----
  {
    int qq = tid & 31;                 // query
    int qi = qq & 15, qt2 = qq >> 4;
    int jb = tid >> 5;                 // 0..7
#pragma unroll
    for (int k = 0; k < 3; k++) {
      int j = jb + 8 * k;
      float l = 0.f;
      if (j < KN) {
        float s = (j < 20) ? part[qt2 * 2][qi][j] + part[qt2 * 2 + 1][qi][j]
                           : Sqex[qq];
        float y = fmaf(CJ[j], s, 1.0f);                     // y >= 1
        l = 0.69314718f * __builtin_amdgcn_logf(y);         // log1p
      }
      l += __shfl_xor(l, 1);  l += __shfl_xor(l, 2);
      l += __shfl_xor(l, 4);  l += __shfl_xor(l, 8);
      l += __shfl_xor(l, 16);                               // sum over 32 queries
      if (qq == 0 && j < KN) ko[j] = l;
    }
  }
  __syncthreads();

  // ---- tiny MLP: 21 -> 10 -> 5 -> 1 ----
  if (tid < 10) {
    float h = b0[tid];
#pragma unroll
    for (int k = 0; k < KN; k++) h = fmaf(w0[tid * KN + k], ko[k], h);
    h0s[tid] = fmaxf(h, 0.f);
  }
  __syncthreads();
  if (tid < 5) {
    float h = b1[tid];
#pragma unroll
    for (int k = 0; k < 10; k++) h = fmaf(w1[tid * 10 + k], h0s[k], h);
    h1s[tid] = fmaxf(h, 0.f);
  }
  __syncthreads();
  if (tid == 0) {
    float h = b2[0];
#pragma unroll
    for (int k = 0; k < 5; k++) h = fmaf(w2[k], h1s[k], h);
    lgbuf[pair * BATCH + b] = h;
  }
}

// ---------- Combine: sigmoid(lg1 - lg2) ----------
__global__ __launch_bounds__(256) void knrm_combine_kernel(
    const float* __restrict__ lgbuf, float* __restrict__ out)
{
  int i = blockIdx.x * 256 + threadIdx.x;
  if (i < BATCH) {
    float z = lgbuf[i] - lgbuf[BATCH + i];
    out[i] = 1.0f / (1.0f + expf(-z));
  }
}

// ---------------- launch ----------------
extern "C" void kernel_launch(void* const* d_in, const int* in_sizes, int n_in,
                              void* d_out, int out_size, void* d_ws, size_t ws_size,
                              hipStream_t stream)
{
  const float* emb = (const float*)d_in[0];
  const float* w0  = (const float*)d_in[1];
  const float* b0  = (const float*)d_in[2];
  const float* w1  = (const float*)d_in[3];
  const float* b1  = (const float*)d_in[4];
  const float* w2  = (const float*)d_in[5];
  const float* b2  = (const float*)d_in[6];
  const int* q1 = (const int*)d_in[7];
  const int* dd1 = (const int*)d_in[8];
  const int* q2 = (const int*)d_in[9];
  const int* dd2 = (const int*)d_in[10];
  float* out = (float*)d_out;

  int vocab = in_sizes[0] / EMB_N;      // 100000
  int B = in_sizes[7] / LQ;             // 2048

  float* lgbuf = (float*)d_ws;                          // 2*B floats = 16 KB
  short* vb  = (short*)(lgbuf + 2 * BATCH);             // 12.8 MB (rne plane)
  short* vlo = vb + (size_t)vocab * KP;                 // 12.8 MB (residual)

  vocab_norm_kernel<<<(vocab + VROWS - 1) / VROWS, 512, 0, stream>>>(emb, vb, vlo, vocab);
  knrm_main_kernel<<<2 * B, 256, 0, stream>>>(vb, vlo, q1, dd1, q2, dd2,
                                              w0, b0, w1, b1, w2, b2, lgbuf);
  knrm_combine_kernel<<<(B + 255) / 256, 256, 0, stream>>>(lgbuf, out);
}